// Round 1
// baseline (320.724 us; speedup 1.0000x reference)
//
#include <hip/hip_runtime.h>
#include <cstdint>
#include <cstddef>

#define NB 2
#define SEQ 2048
#define DMODEL 2048
#define NHEAD 16
#define HDIM 128
#define NGRP 4
#define NKV (NGRP * HDIM)          // 512
#define NQKV (DMODEL + 2 * NKV)    // 3072
#define MROWS (NB * SEQ)           // 4096

typedef unsigned short u16_t;
typedef unsigned int u32_t;
typedef __bf16 bf16x8 __attribute__((ext_vector_type(8)));
typedef float f32x4 __attribute__((ext_vector_type(4)));

static __device__ __forceinline__ u16_t f2bf(float f) {
  u32_t u = __builtin_bit_cast(u32_t, f);
  u32_t r = u + 0x7FFFu + ((u >> 16) & 1u);
  return (u16_t)(r >> 16);
}

// ---------------- prep kernels ----------------

__global__ void k_cast_x(const float* __restrict__ x, u16_t* __restrict__ xb) {
  int i = blockIdx.x * 256 + threadIdx.x;          // group of 4 floats
  float4 v = ((const float4*)x)[i];
  uint2 pk;
  pk.x = (u32_t)f2bf(v.x) | ((u32_t)f2bf(v.y) << 16);
  pk.y = (u32_t)f2bf(v.z) | ((u32_t)f2bf(v.w) << 16);
  ((uint2*)xb)[i] = pk;
}

__global__ void k_tables(const float* __restrict__ rf, float* __restrict__ cosT,
                         float* __restrict__ sinT) {
  int i = blockIdx.x * 256 + threadIdx.x;          // < SEQ*HDIM/2
  float f = rf[i];
  cosT[i] = cosf(f);
  sinT[i] = sinf(f);
}

__global__ void k_bias(const float* __restrict__ bq, const float* __restrict__ bk,
                       const float* __restrict__ bv, float* __restrict__ bqkv) {
  int i = blockIdx.x * 256 + threadIdx.x;          // < NQKV
  float v = (i < DMODEL) ? bq[i] : (i < DMODEL + NKV ? bk[i - DMODEL] : bv[i - DMODEL - NKV]);
  bqkv[i] = v;
}

// W: [K][N] fp32 row-major -> Wt: [N][K] bf16 row-major
__global__ void k_transpose_cast(const float* __restrict__ W, int N,
                                 u16_t* __restrict__ Wt, int K) {
  __shared__ float tile[64][65];
  int n0 = blockIdx.x * 64, k0 = blockIdx.y * 64;
  int t = threadIdx.x;
#pragma unroll
  for (int pass = 0; pass < 4; ++pass) {
    int slot = pass * 256 + t;
    int r = slot >> 4, c4 = (slot & 15) * 4;
    float4 v = *(const float4*)(W + (size_t)(k0 + r) * N + n0 + c4);
    tile[r][c4] = v.x; tile[r][c4 + 1] = v.y; tile[r][c4 + 2] = v.z; tile[r][c4 + 3] = v.w;
  }
  __syncthreads();
  int nr = t >> 2, seg = t & 3;
  alignas(16) u16_t o[16];
#pragma unroll
  for (int kk = 0; kk < 16; ++kk) o[kk] = f2bf(tile[seg * 16 + kk][nr]);
  u16_t* dst = Wt + (size_t)(n0 + nr) * K + k0 + seg * 16;
  ((int4*)dst)[0] = ((const int4*)o)[0];
  ((int4*)dst)[1] = ((const int4*)o)[1];
}

// ---------------- GEMM: C[M][N] = A[M][K](bf16) * Bt[N][K](bf16)^T + bias ----------------
// EPI 0: fp32 out.  EPI 1: QKV epilogue (RoPE on Q/K, V transposed), bf16 out.

template <int EPI>
__global__ __launch_bounds__(256, 2) void k_gemm(
    const u16_t* __restrict__ A, const u16_t* __restrict__ Bt, const float* __restrict__ bias,
    float* __restrict__ Cout, u16_t* __restrict__ Qb, u16_t* __restrict__ Kb,
    u16_t* __restrict__ Vt, const float* __restrict__ cosT, const float* __restrict__ sinT,
    int M, int N, int K) {
  __shared__ u16_t A_lds[128 * 32];
  __shared__ u16_t B_lds[128 * 32];
  int tid = threadIdx.x;
  int wid = tid >> 6, lane = tid & 63;
  int l15 = lane & 15, l4 = lane >> 4;
  int m0 = blockIdx.y * 128, n0 = blockIdx.x * 128;
  int wrow = wid >> 1, wcol = wid & 1;
  f32x4 acc[4][4] = {};

  for (int kt = 0; kt < K; kt += 32) {
#pragma unroll
    for (int ss = 0; ss < 2; ++ss) {
      int slot = tid + ss * 256;
      int row = slot >> 2, part = slot & 3;
      __builtin_amdgcn_global_load_lds(
          (const __attribute__((address_space(1))) u32_t*)(A + (size_t)(m0 + row) * K + kt + part * 8),
          (__attribute__((address_space(3))) u32_t*)(A_lds + slot * 8), 16, 0, 0);
      __builtin_amdgcn_global_load_lds(
          (const __attribute__((address_space(1))) u32_t*)(Bt + (size_t)(n0 + row) * K + kt + part * 8),
          (__attribute__((address_space(3))) u32_t*)(B_lds + slot * 8), 16, 0, 0);
    }
    __syncthreads();
    bf16x8 af[4], bfr[4];
#pragma unroll
    for (int i = 0; i < 4; ++i)
      af[i] = *(const bf16x8*)(A_lds + (wrow * 64 + i * 16 + l15) * 32 + l4 * 8);
#pragma unroll
    for (int j = 0; j < 4; ++j)
      bfr[j] = *(const bf16x8*)(B_lds + (wcol * 64 + j * 16 + l15) * 32 + l4 * 8);
#pragma unroll
    for (int i = 0; i < 4; ++i)
#pragma unroll
      for (int j = 0; j < 4; ++j)
        acc[i][j] = __builtin_amdgcn_mfma_f32_16x16x32_bf16(af[i], bfr[j], acc[i][j], 0, 0, 0);
    __syncthreads();
  }

  if (EPI == 0) {
#pragma unroll
    for (int j = 0; j < 4; ++j) {
      int n = n0 + wcol * 64 + j * 16 + l15;
      float bs = bias[n];
#pragma unroll
      for (int i = 0; i < 4; ++i) {
        int mbase = m0 + wrow * 64 + i * 16 + l4 * 4;
#pragma unroll
        for (int r = 0; r < 4; ++r)
          Cout[(size_t)(mbase + r) * N + n] = acc[i][j][r] + bs;
      }
    }
  } else {
    bool isV = (n0 >= DMODEL + NKV);
    bool isK = (n0 >= DMODEL) && !isV;
#pragma unroll
    for (int j = 0; j < 4; ++j) {
      int n = n0 + wcol * 64 + j * 16 + l15;
      float bs = bias[n];
      int d = n & (HDIM - 1);
      int p = d >> 1;
      bool evn = !(d & 1);
#pragma unroll
      for (int i = 0; i < 4; ++i) {
        int mbase = m0 + wrow * 64 + i * 16 + l4 * 4;
        if (isV) {
          int g = (n - DMODEL - NKV) >> 7;
          int b = mbase >> 11, s0 = mbase & (SEQ - 1);
          u16_t o[4];
#pragma unroll
          for (int r = 0; r < 4; ++r) o[r] = f2bf(acc[i][j][r] + bs);
          uint2 pk;
          pk.x = (u32_t)o[0] | ((u32_t)o[1] << 16);
          pk.y = (u32_t)o[2] | ((u32_t)o[3] << 16);
          *(uint2*)(Vt + ((size_t)(b * NGRP + g) * HDIM + d) * SEQ + s0) = pk;
        } else {
#pragma unroll
          for (int r = 0; r < 4; ++r) {
            int m = mbase + r;
            int b = m >> 11, s = m & (SEQ - 1);
            float val = acc[i][j][r] + bs;
            float pv = __shfl_xor(val, 1);
            float c = cosT[s * (HDIM / 2) + p];
            float sn = sinT[s * (HDIM / 2) + p];
            float outv = evn ? (val * c - pv * sn) : (pv * sn + val * c);
            if (isK) {
              int g = (n - DMODEL) >> 7;
              Kb[((size_t)(b * NGRP + g) * SEQ + s) * HDIM + d] = f2bf(outv);
            } else {
              int h = n >> 7;
              Qb[((size_t)(b * NHEAD + h) * SEQ + s) * HDIM + d] = f2bf(outv);
            }
          }
        }
      }
    }
  }
}

// ---------------- flash attention ----------------
// grid: (SEQ/64, NB*NHEAD); 4 waves, each owns 16 q rows. KV tile = 64.

__global__ __launch_bounds__(256, 2) void k_attn(
    const u16_t* __restrict__ Qb, const u16_t* __restrict__ Kb, const u16_t* __restrict__ Vt,
    u16_t* __restrict__ attn_out) {
  __shared__ u16_t K_lds[64 * 136];   // [kv][d], pad 128->136
  __shared__ u16_t V_lds[128 * 72];   // [d][kv], pad 64->72
  __shared__ u16_t P_lds[4 * 16 * 72];

  int tid = threadIdx.x, wid = tid >> 6, lane = tid & 63;
  int l15 = lane & 15, l4 = lane >> 4;
  int bh = blockIdx.y;
  int b = bh >> 4, h = bh & 15, g = h >> 2;
  int q0 = blockIdx.x * 64;
  const u16_t* Qhead = Qb + (size_t)(b * NHEAD + h) * SEQ * HDIM;
  const u16_t* Khead = Kb + (size_t)(b * NGRP + g) * SEQ * HDIM;
  const u16_t* Vhead = Vt + (size_t)(b * NGRP + g) * HDIM * SEQ;

  bf16x8 qf[4];
#pragma unroll
  for (int kc = 0; kc < 4; ++kc)
    qf[kc] = *(const bf16x8*)(Qhead + (size_t)(q0 + wid * 16 + l15) * HDIM + kc * 32 + l4 * 8);

  f32x4 o_acc[8] = {};
  float m_run[4], l_run[4];
#pragma unroll
  for (int r = 0; r < 4; ++r) { m_run[r] = -__builtin_inff(); l_run[r] = 0.f; }

  const float scale = 0.08838834764831845f;  // 1/sqrt(128)

  for (int kv0 = 0; kv0 < SEQ; kv0 += 64) {
#pragma unroll
    for (int ss = 0; ss < 4; ++ss) {
      int slot = tid + ss * 256;
      int row = slot >> 4, part = slot & 15;
      *(int4*)(K_lds + row * 136 + part * 8) =
          *(const int4*)(Khead + (size_t)(kv0 + row) * HDIM + part * 8);
      int rowv = slot >> 3, partv = slot & 7;
      *(int4*)(V_lds + rowv * 72 + partv * 8) =
          *(const int4*)(Vhead + (size_t)rowv * SEQ + kv0 + partv * 8);
    }
    __syncthreads();

    f32x4 sacc[4] = {};
#pragma unroll
    for (int kc = 0; kc < 4; ++kc) {
#pragma unroll
      for (int kvb = 0; kvb < 4; ++kvb) {
        bf16x8 kf = *(const bf16x8*)(K_lds + (kvb * 16 + l15) * 136 + kc * 32 + l4 * 8);
        sacc[kvb] = __builtin_amdgcn_mfma_f32_16x16x32_bf16(qf[kc], kf, sacc[kvb], 0, 0, 0);
      }
    }
#pragma unroll
    for (int kvb = 0; kvb < 4; ++kvb)
#pragma unroll
      for (int r = 0; r < 4; ++r) sacc[kvb][r] *= scale;

    float tmax[4];
#pragma unroll
    for (int r = 0; r < 4; ++r)
      tmax[r] = fmaxf(fmaxf(sacc[0][r], sacc[1][r]), fmaxf(sacc[2][r], sacc[3][r]));
#pragma unroll
    for (int xm = 1; xm < 16; xm <<= 1)
#pragma unroll
      for (int r = 0; r < 4; ++r) tmax[r] = fmaxf(tmax[r], __shfl_xor(tmax[r], xm));

    float mnew[4], corr[4];
#pragma unroll
    for (int r = 0; r < 4; ++r) {
      mnew[r] = fmaxf(m_run[r], tmax[r]);
      corr[r] = __expf(m_run[r] - mnew[r]);
      m_run[r] = mnew[r];
    }

    float tsum[4] = {0.f, 0.f, 0.f, 0.f};
#pragma unroll
    for (int kvb = 0; kvb < 4; ++kvb) {
#pragma unroll
      for (int r = 0; r < 4; ++r) {
        float pv = __expf(sacc[kvb][r] - mnew[r]);
        tsum[r] += pv;
        P_lds[(wid * 16 + l4 * 4 + r) * 72 + kvb * 16 + l15] = f2bf(pv);
      }
    }
#pragma unroll
    for (int xm = 1; xm < 16; xm <<= 1)
#pragma unroll
      for (int r = 0; r < 4; ++r) tsum[r] += __shfl_xor(tsum[r], xm);
#pragma unroll
    for (int r = 0; r < 4; ++r) l_run[r] = l_run[r] * corr[r] + tsum[r];

#pragma unroll
    for (int dcb = 0; dcb < 8; ++dcb)
#pragma unroll
      for (int r = 0; r < 4; ++r) o_acc[dcb][r] *= corr[r];

#pragma unroll
    for (int kc2 = 0; kc2 < 2; ++kc2) {
      bf16x8 pf = *(const bf16x8*)(P_lds + (wid * 16 + l15) * 72 + kc2 * 32 + l4 * 8);
#pragma unroll
      for (int dcb = 0; dcb < 8; ++dcb) {
        bf16x8 vf = *(const bf16x8*)(V_lds + (dcb * 16 + l15) * 72 + kc2 * 32 + l4 * 8);
        o_acc[dcb] = __builtin_amdgcn_mfma_f32_16x16x32_bf16(pf, vf, o_acc[dcb], 0, 0, 0);
      }
    }
    __syncthreads();
  }

#pragma unroll
  for (int dcb = 0; dcb < 8; ++dcb) {
#pragma unroll
    for (int r = 0; r < 4; ++r) {
      int s = q0 + wid * 16 + l4 * 4 + r;
      float val = o_acc[dcb][r] / l_run[r];
      attn_out[((size_t)(b * SEQ + s)) * DMODEL + h * HDIM + dcb * 16 + l15] = f2bf(val);
    }
  }
}

// ---------------- launcher ----------------

extern "C" void kernel_launch(void* const* d_in, const int* in_sizes, int n_in,
                              void* d_out, int out_size, void* d_ws, size_t ws_size,
                              hipStream_t stream) {
  (void)in_sizes; (void)n_in; (void)out_size; (void)ws_size;
  const float* x  = (const float*)d_in[0];
  const float* rf = (const float*)d_in[1];
  const float* Wq = (const float*)d_in[2];
  const float* bq = (const float*)d_in[3];
  const float* Wk = (const float*)d_in[4];
  const float* bk = (const float*)d_in[5];
  const float* Wv = (const float*)d_in[6];
  const float* bv = (const float*)d_in[7];
  const float* Wo = (const float*)d_in[8];
  const float* bo = (const float*)d_in[9];
  float* out = (float*)d_out;

  char* ws = (char*)d_ws;
  u16_t* xb    = (u16_t*)ws;  ws += (size_t)MROWS * DMODEL * 2;
  u16_t* Wqkvt = (u16_t*)ws;  ws += (size_t)NQKV * DMODEL * 2;
  u16_t* Wot   = (u16_t*)ws;  ws += (size_t)DMODEL * DMODEL * 2;
  float* bqkv  = (float*)ws;  ws += (size_t)NQKV * 4;
  float* cosT  = (float*)ws;  ws += (size_t)SEQ * (HDIM / 2) * 4;
  float* sinT  = (float*)ws;  ws += (size_t)SEQ * (HDIM / 2) * 4;
  u16_t* Qb    = (u16_t*)ws;  ws += (size_t)NB * NHEAD * SEQ * HDIM * 2;
  u16_t* Kb    = (u16_t*)ws;  ws += (size_t)NB * NGRP * SEQ * HDIM * 2;
  u16_t* Vt    = (u16_t*)ws;  ws += (size_t)NB * NGRP * HDIM * SEQ * 2;
  u16_t* attn  = xb;  // alias: xb dead after GEMM1 (strict stream ordering)

  k_cast_x<<<MROWS * DMODEL / 1024, 256, 0, stream>>>(x, xb);
  k_tables<<<SEQ * (HDIM / 2) / 256, 256, 0, stream>>>(rf, cosT, sinT);
  k_bias<<<NQKV / 256, 256, 0, stream>>>(bq, bk, bv, bqkv);

  dim3 tgq(DMODEL / 64, DMODEL / 64);
  dim3 tgk(NKV / 64, DMODEL / 64);
  k_transpose_cast<<<tgq, 256, 0, stream>>>(Wq, DMODEL, Wqkvt, DMODEL);
  k_transpose_cast<<<tgk, 256, 0, stream>>>(Wk, NKV, Wqkvt + (size_t)DMODEL * DMODEL, DMODEL);
  k_transpose_cast<<<tgk, 256, 0, stream>>>(Wv, NKV, Wqkvt + (size_t)(DMODEL + NKV) * DMODEL, DMODEL);
  k_transpose_cast<<<tgq, 256, 0, stream>>>(Wo, DMODEL, Wot, DMODEL);

  dim3 g1(NQKV / 128, MROWS / 128);
  k_gemm<1><<<g1, 256, 0, stream>>>(xb, Wqkvt, bqkv, nullptr, Qb, Kb, Vt, cosT, sinT,
                                    MROWS, NQKV, DMODEL);
  dim3 ga(SEQ / 64, NB * NHEAD);
  k_attn<<<ga, 256, 0, stream>>>(Qb, Kb, Vt, attn);
  dim3 g2(DMODEL / 128, MROWS / 128);
  k_gemm<0><<<g2, 256, 0, stream>>>(attn, Wot, bo, out, nullptr, nullptr, nullptr,
                                    nullptr, nullptr, MROWS, DMODEL, DMODEL);
}